// Round 19
// baseline (109.526 us; speedup 1.0000x reference)
//
#include <hip/hip_runtime.h>
#include <hip/hip_bf16.h>
#include <math.h>

#define B_ 2
#define H_ 16
#define N_ 8192
#define D_ 64
#define R_ 7
#define BLOCK_ 256
#define SAMPLE_ 256
#define BH_ (B_*H_)
#define NBLK_ (N_/BLOCK_)

#define CHUNK_ 128           // keys staged per chunk
#define PADK 72              // Ks row stride: 144 B
#define PADV 132             // Vt row stride: 264 B

typedef __attribute__((ext_vector_type(8))) short bf16x8;
typedef __attribute__((ext_vector_type(4))) short bf16x4;
typedef __attribute__((ext_vector_type(4))) float f32x4;
typedef __attribute__((ext_vector_type(2))) unsigned int u32x2;
typedef __attribute__((ext_vector_type(4))) unsigned int u32x4;

__device__ inline unsigned short f2bf(float x) {
  __hip_bfloat16 h = __float2bfloat16(x);
  return *(unsigned short*)&h;
}
__device__ inline unsigned int pack2bf(float a, float b) {
  return (unsigned int)f2bf(a) | ((unsigned int)f2bf(b) << 16);
}
__device__ inline float fexp2(float x) {
#if __has_builtin(__builtin_amdgcn_exp2f)
  return __builtin_amdgcn_exp2f(x);
#else
  return exp2f(x);
#endif
}

// ---------------- Kernel 1: LSH hash (R10 — b128 broadcast spdT) ----------------
__global__ __launch_bounds__(256) void hash_kernel(
    const float* __restrict__ q, const float* __restrict__ k,
    const float* __restrict__ pd, int* __restrict__ qh, int* __restrict__ kh) {
  __shared__ __align__(16) float spdT[R_][D_];   // [r][d]
  for (int i = threadIdx.x; i < D_ * R_; i += blockDim.x) {
    int d = i / R_, r = i - d * R_;              // pd[d*R + r]
    spdT[r][d] = pd[i];
  }
  __syncthreads();
  int tid = blockIdx.x * blockDim.x + threadIdx.x;
  const int half = BH_ * N_;
  const float* src = (tid < half) ? q : k;
  int* dst = (tid < half) ? qh : kh;
  int row = (tid < half) ? tid : tid - half;
  const float4* x4 = (const float4*)(src + (size_t)row * D_);
  float4 x[16];
#pragma unroll
  for (int j = 0; j < 16; j++) x[j] = x4[j];
  int bin = 0;
#pragma unroll
  for (int r = 0; r < R_; r++) {
    float a = 0.f;
#pragma unroll
    for (int j = 0; j < 16; j++) {
      float4 sp = *(const float4*)&spdT[r][4 * j];
      a = fmaf(x[j].x, sp.x, a);
      a = fmaf(x[j].y, sp.y, a);
      a = fmaf(x[j].z, sp.z, a);
      a = fmaf(x[j].w, sp.w, a);
    }
    bin |= (a > 0.f) ? (1 << r) : 0;
  }
  dst[row] = bin ^ (bin >> 1);
}

// ---------------- Kernel 2: stable counting sort, 256 threads/WG (R10) ----------------
__global__ __launch_bounds__(256) void sort_kernel(
    const int* __restrict__ qh, const int* __restrict__ kh,
    int* __restrict__ qidx, int* __restrict__ kidx) {
  int g = blockIdx.x;
  int bh = g & (BH_ - 1);
  bool isK = g >= BH_;
  const int* h = (isK ? kh : qh) + (size_t)bh * N_;
  int* idx = (isK ? kidx : qidx) + (size_t)bh * N_;
  __shared__ unsigned short hist[128][256];   // 64 KiB
  __shared__ int segsum[128][8];
  __shared__ int tot[128];
  __shared__ int off[128];
  const int t = threadIdx.x;

  {  // zero hist (u32x4 = 16 B stores)
    u32x4* hz = (u32x4*)hist;
    for (int i = t; i < 4096; i += 256) hz[i] = (u32x4){0u, 0u, 0u, 0u};
  }
  __syncthreads();

  const int base = t * 32;
  int hv[32];
#pragma unroll
  for (int j = 0; j < 32; j++) hv[j] = h[base + j];
#pragma unroll
  for (int j = 0; j < 32; j++) hist[hv[j]][t]++;
  __syncthreads();

  for (int task = t; task < 1024; task += 256) {
    int b = task >> 3, s = task & 7;
    int sum = 0;
#pragma unroll
    for (int u = 0; u < 32; u++) sum += hist[b][s * 32 + u];
    segsum[b][s] = sum;
  }
  __syncthreads();

  if (t < 128) {
    int run = 0;
#pragma unroll
    for (int s = 0; s < 8; s++) { int x = segsum[t][s]; segsum[t][s] = run; run += x; }
    tot[t] = run;
  }
  __syncthreads();

  if (t == 0) {
    int run = 0;
    for (int b = 0; b < 128; b++) { off[b] = run; run += tot[b]; }
  }
  __syncthreads();

  for (int task = t; task < 1024; task += 256) {
    int b = task >> 3, s = task & 7;
    int run = off[b] + segsum[b][s];
#pragma unroll
    for (int u = 0; u < 32; u++) {
      int x = hist[b][s * 32 + u];
      hist[b][s * 32 + u] = (unsigned short)run;
      run += x;
    }
  }
  __syncthreads();

#pragma unroll
  for (int j = 0; j < 32; j++) {
    int c = hv[j];
    int p = hist[c][t]++;
    idx[p] = base + j;
  }
}

// ---------------- Kernel 3: MFMA fused attention ----------------
// R18 base + R19: XCD-aware bijective blockIdx swizzle (grid 1024 = 8 XCD x 128):
// wgid = (bid&7)*128 + (bid>>3) — groups each bh's 32 WGs (which share kidx/qidx
// and the SAME 256 sampled K/V rows) onto one XCD's L2 instead of scattering
// them across all 8 (T1 mechanism).
__global__ __launch_bounds__(512, 4) void attn_kernel(
    const float* __restrict__ query, const float* __restrict__ key,
    const float* __restrict__ value,
    const int* __restrict__ qidx, const int* __restrict__ kidx,
    const int* __restrict__ samp, float* __restrict__ out) {
  __shared__ __align__(16) unsigned short KsL[2][CHUNK_ * PADK];   // 36864 B
  __shared__ __align__(16) unsigned short VtL[2][D_ * PADV];       // 33792 B
  __shared__ int sbs[2][CHUNK_];
  __shared__ int qrows[BLOCK_];

  const int wgid = ((blockIdx.x & 7) << 7) + (blockIdx.x >> 3);  // XCD swizzle
  const int bh = wgid / NBLK_;
  const int blk = wgid - bh * NBLK_;
  const int tid = threadIdx.x;
  const int w = tid >> 6;       // wave 0..7
  const int lane = tid & 63;
  const int lg = lane >> 4;
  const int lr = lane & 15;
  const float FOLD = 0.18033688011112042f;   // (1/8) * log2(e)

  // ---- staging: thread -> (k-pair kp 0..63, d-octant dq 0..7) ----
  const int kp = tid >> 3, dq = tid & 7;
  auto stage_kv = [&](int buf, int r0, int r1) {
    const float* kr0 = key + ((size_t)bh * N_ + r0) * D_ + dq * 8;
    const float* kr1 = key + ((size_t)bh * N_ + r1) * D_ + dq * 8;
    const float* vr0 = value + ((size_t)bh * N_ + r0) * D_ + dq * 8;
    const float* vr1 = value + ((size_t)bh * N_ + r1) * D_ + dq * 8;
    const int kbase = 2 * kp;
    float4 ka0 = *(const float4*)(kr0), ka1 = *(const float4*)(kr0 + 4);
    float4 kb0 = *(const float4*)(kr1), kb1 = *(const float4*)(kr1 + 4);
    u32x4 pk0 = (u32x4){pack2bf(ka0.x, ka0.y), pack2bf(ka0.z, ka0.w),
                        pack2bf(ka1.x, ka1.y), pack2bf(ka1.z, ka1.w)};
    u32x4 pk1 = (u32x4){pack2bf(kb0.x, kb0.y), pack2bf(kb0.z, kb0.w),
                        pack2bf(kb1.x, kb1.y), pack2bf(kb1.z, kb1.w)};
    *(u32x4*)&KsL[buf][(kbase + 0) * PADK + dq * 8] = pk0;
    *(u32x4*)&KsL[buf][(kbase + 1) * PADK + dq * 8] = pk1;
    float4 va0 = *(const float4*)(vr0), va1 = *(const float4*)(vr0 + 4);
    float4 vb0 = *(const float4*)(vr1), vb1 = *(const float4*)(vr1 + 4);
    float a[8] = {va0.x, va0.y, va0.z, va0.w, va1.x, va1.y, va1.z, va1.w};
    float b[8] = {vb0.x, vb0.y, vb0.z, vb0.w, vb1.x, vb1.y, vb1.z, vb1.w};
#pragma unroll
    for (int j = 0; j < 8; j++)
      *(unsigned*)&VtL[buf][(dq * 8 + j) * PADV + kbase] = pack2bf(a[j], b[j]);
  };
  auto stage_block = [&](int c, int buf) {
    size_t ib = (size_t)bh * N_ + blk * BLOCK_ + c * CHUNK_ + 2 * kp;
    stage_kv(buf, kidx[ib], kidx[ib + 1]);
  };
  auto stage_sample = [&](int c, int buf) {
    size_t sb = (size_t)bh * SAMPLE_ + c * CHUNK_;
    int p0 = samp[sb + 2 * kp], p1 = samp[sb + 2 * kp + 1];
    int r0 = kidx[(size_t)bh * N_ + p0], r1 = kidx[(size_t)bh * N_ + p1];
    stage_kv(buf, r0, r1);
    if (tid < CHUNK_) sbs[buf][tid] = samp[sb + tid] >> 8;   // pos/BLOCK_
  };

  // ---- prologue: chunk 0 -> buf 0, qrows ----
  stage_block(0, 0);
  if (tid < BLOCK_) qrows[tid] = qidx[(size_t)bh * N_ + blk * BLOCK_ + tid];
  __syncthreads();

  // ---- Q fragments (scale folded): lane holds Q[q=qt*16+lr][d=lg*8+h*32..+8] ----
  bf16x8 qf[2][2];
#pragma unroll
  for (int qt = 0; qt < 2; qt++) {
    int qrow = qrows[w * 32 + qt * 16 + lr];
    const float* qp = query + ((size_t)bh * N_ + qrow) * D_ + lg * 8;
#pragma unroll
    for (int h = 0; h < 2; h++) {
      float4 a = *(const float4*)(qp + h * 32);
      float4 b = *(const float4*)(qp + h * 32 + 4);
      union { u32x4 u; bf16x8 v; } cv;
      cv.u = (u32x4){pack2bf(a.x * FOLD, a.y * FOLD), pack2bf(a.z * FOLD, a.w * FOLD),
                     pack2bf(b.x * FOLD, b.y * FOLD), pack2bf(b.z * FOLD, b.w * FOLD)};
      qf[qt][h] = cv.v;
    }
  }

  // ---- ones A-fragment (8-wide): A[row 0][*]=1 -> D row 0 = col sums of W ----
  const bf16x8 avONE8 = (lr == 0)
      ? (bf16x8){(short)0x3F80, (short)0x3F80, (short)0x3F80, (short)0x3F80,
                 (short)0x3F80, (short)0x3F80, (short)0x3F80, (short)0x3F80}
      : (bf16x8){0, 0, 0, 0, 0, 0, 0, 0};

  // ---- SINGLE accumulator set (linear merge) + ls accumulators on MFMA pipe ----
  f32x4 oX[2][4], oLS[2];
#pragma unroll
  for (int a = 0; a < 2; a++) {
    oLS[a] = (f32x4){0.f, 0.f, 0.f, 0.f};
#pragma unroll
    for (int b = 0; b < 4; b++) oX[a][b] = (f32x4){0.f, 0.f, 0.f, 0.f};
  }

  auto phase = [&](int buf, bool masked) {
    __builtin_amdgcn_s_setprio(1);
#pragma unroll 2
    for (int ktp = 0; ktp < 4; ktp++) {
      const int kta = 2 * ktp, ktb = 2 * ktp + 1;
      const unsigned short* krow0 = &KsL[buf][(kta * 16 + lr) * PADK + lg * 8];
      const unsigned short* krow1 = &KsL[buf][(ktb * 16 + lr) * PADK + lg * 8];
      bf16x8 a0k0 = *(const bf16x8*)(krow0);
      bf16x8 a0k1 = *(const bf16x8*)(krow0 + 32);
      bf16x8 a1k0 = *(const bf16x8*)(krow1);
      bf16x8 a1k1 = *(const bf16x8*)(krow1 + 32);
      // V^T fragments under the pair-permutation: {tile-a 4 keys, tile-b 4 keys}
      bf16x8 av[4];
#pragma unroll
      for (int dt = 0; dt < 4; dt++) {
        const unsigned short* vrow = &VtL[buf][(dt * 16 + lr) * PADV];
        u32x2 lo = *(const u32x2*)(vrow + kta * 16 + lg * 4);
        u32x2 hi = *(const u32x2*)(vrow + ktb * 16 + lg * 4);
        union { u32x4 u; bf16x8 v; } cv;
        cv.u = (u32x4){lo[0], lo[1], hi[0], hi[1]};
        av[dt] = cv.v;
      }
      float mska[4], mskb[4];
      if (masked) {
#pragma unroll
        for (int r = 0; r < 4; r++) {
          mska[r] = (sbs[buf][kta * 16 + lg * 4 + r] == blk) ? 0.f : 32.f;
          mskb[r] = (sbs[buf][ktb * 16 + lg * 4 + r] == blk) ? 0.f : 32.f;
        }
      }
      bf16x8 bq[2];
#pragma unroll
      for (int qt = 0; qt < 2; qt++) {
        f32x4 ca = (f32x4){0.f, 0.f, 0.f, 0.f};
        ca = __builtin_amdgcn_mfma_f32_16x16x32_bf16(a0k0, qf[qt][0], ca, 0, 0, 0);
        ca = __builtin_amdgcn_mfma_f32_16x16x32_bf16(a0k1, qf[qt][1], ca, 0, 0, 0);
        f32x4 cb = (f32x4){0.f, 0.f, 0.f, 0.f};
        cb = __builtin_amdgcn_mfma_f32_16x16x32_bf16(a1k0, qf[qt][0], cb, 0, 0, 0);
        cb = __builtin_amdgcn_mfma_f32_16x16x32_bf16(a1k1, qf[qt][1], cb, 0, 0, 0);
        float wa0 = fexp2(ca[0]), wa1 = fexp2(ca[1]), wa2 = fexp2(ca[2]), wa3 = fexp2(ca[3]);
        float wb0 = fexp2(cb[0]), wb1 = fexp2(cb[1]), wb2 = fexp2(cb[2]), wb3 = fexp2(cb[3]);
        if (masked) {
          wa0 *= mska[0]; wa1 *= mska[1]; wa2 *= mska[2]; wa3 *= mska[3];
          wb0 *= mskb[0]; wb1 *= mskb[1]; wb2 *= mskb[2]; wb3 *= mskb[3];
        }
        union { u32x4 u; bf16x8 v; } cv;
        cv.u = (u32x4){pack2bf(wa0, wa1), pack2bf(wa2, wa3),
                       pack2bf(wb0, wb1), pack2bf(wb2, wb3)};
        bq[qt] = cv.v;
      }
#pragma unroll
      for (int qt = 0; qt < 2; qt++) {
#pragma unroll
        for (int dt = 0; dt < 4; dt++)
          oX[qt][dt] = __builtin_amdgcn_mfma_f32_16x16x32_bf16(av[dt], bq[qt], oX[qt][dt], 0, 0, 0);
        oLS[qt] = __builtin_amdgcn_mfma_f32_16x16x32_bf16(avONE8, bq[qt], oLS[qt], 0, 0, 0);
      }
    }
    __builtin_amdgcn_s_setprio(0);
  };

  // ---- chunks: block0(b0), block1(b1), sample0(b0), sample1(b1) ----
  phase(0, false);
  stage_block(1, 1);       // into other buffer; no pre-barrier needed
  __syncthreads();

  phase(1, false);
  stage_sample(0, 0);
  __syncthreads();

  phase(0, true);
  stage_sample(1, 1);
  __syncthreads();

  phase(1, true);

  // ---- normalize + scatter: out = oX / ls ----
#pragma unroll
  for (int qt = 0; qt < 2; qt++) {
    float l = __shfl(oLS[qt][0], lr);   // lane (lg=0, lr) holds sum for q=lr
    float winv = 1.f / l;
    int qr = qrows[w * 32 + qt * 16 + lr];
    float* op = out + ((size_t)bh * N_ + qr) * D_ + lg * 4;
#pragma unroll
    for (int dt = 0; dt < 4; dt++) {
      float4 o;
      o.x = winv * oX[qt][dt][0];
      o.y = winv * oX[qt][dt][1];
      o.z = winv * oX[qt][dt][2];
      o.w = winv * oX[qt][dt][3];
      *(float4*)(op + dt * 16) = o;
    }
  }
}

extern "C" void kernel_launch(void* const* d_in, const int* in_sizes, int n_in,
                              void* d_out, int out_size, void* d_ws, size_t ws_size,
                              hipStream_t stream) {
  const float* query = (const float*)d_in[0];
  const float* key   = (const float*)d_in[1];
  const float* value = (const float*)d_in[2];
  const float* pd    = (const float*)d_in[3];
  const int*   samp  = (const int*)d_in[4];
  float* out = (float*)d_out;

  char* w = (char*)d_ws;
  size_t o = 0;
  auto alloc = [&](size_t bytes) { void* p = w + o; o = (o + bytes + 255) & ~(size_t)255; return p; };
  int* qh   = (int*)alloc((size_t)BH_ * N_ * 4);
  int* kh   = (int*)alloc((size_t)BH_ * N_ * 4);
  int* qidx = (int*)alloc((size_t)BH_ * N_ * 4);
  int* kidx = (int*)alloc((size_t)BH_ * N_ * 4);

  hash_kernel<<<(2 * BH_ * N_) / 256, 256, 0, stream>>>(query, key, pd, qh, kh);
  sort_kernel<<<2 * BH_, 256, 0, stream>>>(qh, kh, qidx, kidx);
  attn_kernel<<<BH_ * NBLK_, 512, 0, stream>>>(query, key, value, qidx, kidx,
                                               samp, out);
}

// Round 20
// 109.118 us; speedup vs baseline: 1.0037x; 1.0037x over previous
//
#include <hip/hip_runtime.h>
#include <hip/hip_bf16.h>
#include <math.h>

#define B_ 2
#define H_ 16
#define N_ 8192
#define D_ 64
#define R_ 7
#define BLOCK_ 256
#define SAMPLE_ 256
#define BH_ (B_*H_)
#define NBLK_ (N_/BLOCK_)

#define CHUNK_ 128           // keys staged per chunk
#define PADK 72              // Ks row stride: 144 B
#define PADV 132             // Vt row stride: 264 B

typedef __attribute__((ext_vector_type(8))) short bf16x8;
typedef __attribute__((ext_vector_type(4))) short bf16x4;
typedef __attribute__((ext_vector_type(4))) float f32x4;
typedef __attribute__((ext_vector_type(2))) unsigned int u32x2;
typedef __attribute__((ext_vector_type(4))) unsigned int u32x4;

__device__ inline unsigned short f2bf(float x) {
  __hip_bfloat16 h = __float2bfloat16(x);
  return *(unsigned short*)&h;
}
__device__ inline unsigned int pack2bf(float a, float b) {
  return (unsigned int)f2bf(a) | ((unsigned int)f2bf(b) << 16);
}
__device__ inline float fexp2(float x) {
#if __has_builtin(__builtin_amdgcn_exp2f)
  return __builtin_amdgcn_exp2f(x);
#else
  return exp2f(x);
#endif
}

// ---------------- Kernel 1: LSH hash (b128 broadcast spdT) ----------------
__global__ __launch_bounds__(256) void hash_kernel(
    const float* __restrict__ q, const float* __restrict__ k,
    const float* __restrict__ pd, int* __restrict__ qh, int* __restrict__ kh) {
  __shared__ __align__(16) float spdT[R_][D_];   // [r][d]
  for (int i = threadIdx.x; i < D_ * R_; i += blockDim.x) {
    int d = i / R_, r = i - d * R_;              // pd[d*R + r]
    spdT[r][d] = pd[i];
  }
  __syncthreads();
  int tid = blockIdx.x * blockDim.x + threadIdx.x;
  const int half = BH_ * N_;
  const float* src = (tid < half) ? q : k;
  int* dst = (tid < half) ? qh : kh;
  int row = (tid < half) ? tid : tid - half;
  const float4* x4 = (const float4*)(src + (size_t)row * D_);
  float4 x[16];
#pragma unroll
  for (int j = 0; j < 16; j++) x[j] = x4[j];
  int bin = 0;
#pragma unroll
  for (int r = 0; r < R_; r++) {
    float a = 0.f;
#pragma unroll
    for (int j = 0; j < 16; j++) {
      float4 sp = *(const float4*)&spdT[r][4 * j];
      a = fmaf(x[j].x, sp.x, a);
      a = fmaf(x[j].y, sp.y, a);
      a = fmaf(x[j].z, sp.z, a);
      a = fmaf(x[j].w, sp.w, a);
    }
    bin |= (a > 0.f) ? (1 << r) : 0;
  }
  dst[row] = bin ^ (bin >> 1);
}

// ---------------- Kernel 2: stable counting sort, 256 threads/WG ----------------
__global__ __launch_bounds__(256) void sort_kernel(
    const int* __restrict__ qh, const int* __restrict__ kh,
    int* __restrict__ qidx, int* __restrict__ kidx) {
  int g = blockIdx.x;
  int bh = g & (BH_ - 1);
  bool isK = g >= BH_;
  const int* h = (isK ? kh : qh) + (size_t)bh * N_;
  int* idx = (isK ? kidx : qidx) + (size_t)bh * N_;
  __shared__ unsigned short hist[128][256];   // 64 KiB
  __shared__ int segsum[128][8];
  __shared__ int tot[128];
  __shared__ int off[128];
  const int t = threadIdx.x;

  {  // zero hist (u32x4 = 16 B stores)
    u32x4* hz = (u32x4*)hist;
    for (int i = t; i < 4096; i += 256) hz[i] = (u32x4){0u, 0u, 0u, 0u};
  }
  __syncthreads();

  const int base = t * 32;
  int hv[32];
#pragma unroll
  for (int j = 0; j < 32; j++) hv[j] = h[base + j];
#pragma unroll
  for (int j = 0; j < 32; j++) hist[hv[j]][t]++;
  __syncthreads();

  for (int task = t; task < 1024; task += 256) {
    int b = task >> 3, s = task & 7;
    int sum = 0;
#pragma unroll
    for (int u = 0; u < 32; u++) sum += hist[b][s * 32 + u];
    segsum[b][s] = sum;
  }
  __syncthreads();

  if (t < 128) {
    int run = 0;
#pragma unroll
    for (int s = 0; s < 8; s++) { int x = segsum[t][s]; segsum[t][s] = run; run += x; }
    tot[t] = run;
  }
  __syncthreads();

  if (t == 0) {
    int run = 0;
    for (int b = 0; b < 128; b++) { off[b] = run; run += tot[b]; }
  }
  __syncthreads();

  for (int task = t; task < 1024; task += 256) {
    int b = task >> 3, s = task & 7;
    int run = off[b] + segsum[b][s];
#pragma unroll
    for (int u = 0; u < 32; u++) {
      int x = hist[b][s * 32 + u];
      hist[b][s * 32 + u] = (unsigned short)run;
      run += x;
    }
  }
  __syncthreads();

#pragma unroll
  for (int j = 0; j < 32; j++) {
    int c = hv[j];
    int p = hist[c][t]++;
    idx[p] = base + j;
  }
}

// ---------------- Kernel 3: MFMA fused attention (R18 — best measured) ----------------
// dbuf LDS, linear merge (out = (oA+32*oB)/(lA+32*lB)), direct sample gather,
// ls on MFMA pipe via ones-fragment, PV fused over kt-pairs with 16x16x32.
__global__ __launch_bounds__(512, 4) void attn_kernel(
    const float* __restrict__ query, const float* __restrict__ key,
    const float* __restrict__ value,
    const int* __restrict__ qidx, const int* __restrict__ kidx,
    const int* __restrict__ samp, float* __restrict__ out) {
  __shared__ __align__(16) unsigned short KsL[2][CHUNK_ * PADK];   // 36864 B
  __shared__ __align__(16) unsigned short VtL[2][D_ * PADV];       // 33792 B
  __shared__ int sbs[2][CHUNK_];
  __shared__ int qrows[BLOCK_];

  const int bh = blockIdx.x / NBLK_;
  const int blk = blockIdx.x - bh * NBLK_;
  const int tid = threadIdx.x;
  const int w = tid >> 6;       // wave 0..7
  const int lane = tid & 63;
  const int lg = lane >> 4;
  const int lr = lane & 15;
  const float FOLD = 0.18033688011112042f;   // (1/8) * log2(e)

  // ---- staging: thread -> (k-pair kp 0..63, d-octant dq 0..7) ----
  const int kp = tid >> 3, dq = tid & 7;
  auto stage_kv = [&](int buf, int r0, int r1) {
    const float* kr0 = key + ((size_t)bh * N_ + r0) * D_ + dq * 8;
    const float* kr1 = key + ((size_t)bh * N_ + r1) * D_ + dq * 8;
    const float* vr0 = value + ((size_t)bh * N_ + r0) * D_ + dq * 8;
    const float* vr1 = value + ((size_t)bh * N_ + r1) * D_ + dq * 8;
    const int kbase = 2 * kp;
    float4 ka0 = *(const float4*)(kr0), ka1 = *(const float4*)(kr0 + 4);
    float4 kb0 = *(const float4*)(kr1), kb1 = *(const float4*)(kr1 + 4);
    u32x4 pk0 = (u32x4){pack2bf(ka0.x, ka0.y), pack2bf(ka0.z, ka0.w),
                        pack2bf(ka1.x, ka1.y), pack2bf(ka1.z, ka1.w)};
    u32x4 pk1 = (u32x4){pack2bf(kb0.x, kb0.y), pack2bf(kb0.z, kb0.w),
                        pack2bf(kb1.x, kb1.y), pack2bf(kb1.z, kb1.w)};
    *(u32x4*)&KsL[buf][(kbase + 0) * PADK + dq * 8] = pk0;
    *(u32x4*)&KsL[buf][(kbase + 1) * PADK + dq * 8] = pk1;
    float4 va0 = *(const float4*)(vr0), va1 = *(const float4*)(vr0 + 4);
    float4 vb0 = *(const float4*)(vr1), vb1 = *(const float4*)(vr1 + 4);
    float a[8] = {va0.x, va0.y, va0.z, va0.w, va1.x, va1.y, va1.z, va1.w};
    float b[8] = {vb0.x, vb0.y, vb0.z, vb0.w, vb1.x, vb1.y, vb1.z, vb1.w};
#pragma unroll
    for (int j = 0; j < 8; j++)
      *(unsigned*)&VtL[buf][(dq * 8 + j) * PADV + kbase] = pack2bf(a[j], b[j]);
  };
  auto stage_block = [&](int c, int buf) {
    size_t ib = (size_t)bh * N_ + blk * BLOCK_ + c * CHUNK_ + 2 * kp;
    stage_kv(buf, kidx[ib], kidx[ib + 1]);
  };
  auto stage_sample = [&](int c, int buf) {
    size_t sb = (size_t)bh * SAMPLE_ + c * CHUNK_;
    int p0 = samp[sb + 2 * kp], p1 = samp[sb + 2 * kp + 1];
    int r0 = kidx[(size_t)bh * N_ + p0], r1 = kidx[(size_t)bh * N_ + p1];
    stage_kv(buf, r0, r1);
    if (tid < CHUNK_) sbs[buf][tid] = samp[sb + tid] >> 8;   // pos/BLOCK_
  };

  // ---- prologue: chunk 0 -> buf 0, qrows ----
  stage_block(0, 0);
  if (tid < BLOCK_) qrows[tid] = qidx[(size_t)bh * N_ + blk * BLOCK_ + tid];
  __syncthreads();

  // ---- Q fragments (scale folded): lane holds Q[q=qt*16+lr][d=lg*8+h*32..+8] ----
  bf16x8 qf[2][2];
#pragma unroll
  for (int qt = 0; qt < 2; qt++) {
    int qrow = qrows[w * 32 + qt * 16 + lr];
    const float* qp = query + ((size_t)bh * N_ + qrow) * D_ + lg * 8;
#pragma unroll
    for (int h = 0; h < 2; h++) {
      float4 a = *(const float4*)(qp + h * 32);
      float4 b = *(const float4*)(qp + h * 32 + 4);
      union { u32x4 u; bf16x8 v; } cv;
      cv.u = (u32x4){pack2bf(a.x * FOLD, a.y * FOLD), pack2bf(a.z * FOLD, a.w * FOLD),
                     pack2bf(b.x * FOLD, b.y * FOLD), pack2bf(b.z * FOLD, b.w * FOLD)};
      qf[qt][h] = cv.v;
    }
  }

  // ---- ones A-fragment (8-wide): A[row 0][*]=1 -> D row 0 = col sums of W ----
  const bf16x8 avONE8 = (lr == 0)
      ? (bf16x8){(short)0x3F80, (short)0x3F80, (short)0x3F80, (short)0x3F80,
                 (short)0x3F80, (short)0x3F80, (short)0x3F80, (short)0x3F80}
      : (bf16x8){0, 0, 0, 0, 0, 0, 0, 0};

  // ---- SINGLE accumulator set (linear merge) + ls accumulators on MFMA pipe ----
  f32x4 oX[2][4], oLS[2];
#pragma unroll
  for (int a = 0; a < 2; a++) {
    oLS[a] = (f32x4){0.f, 0.f, 0.f, 0.f};
#pragma unroll
    for (int b = 0; b < 4; b++) oX[a][b] = (f32x4){0.f, 0.f, 0.f, 0.f};
  }

  auto phase = [&](int buf, bool masked) {
    __builtin_amdgcn_s_setprio(1);
#pragma unroll 2
    for (int ktp = 0; ktp < 4; ktp++) {
      const int kta = 2 * ktp, ktb = 2 * ktp + 1;
      const unsigned short* krow0 = &KsL[buf][(kta * 16 + lr) * PADK + lg * 8];
      const unsigned short* krow1 = &KsL[buf][(ktb * 16 + lr) * PADK + lg * 8];
      bf16x8 a0k0 = *(const bf16x8*)(krow0);
      bf16x8 a0k1 = *(const bf16x8*)(krow0 + 32);
      bf16x8 a1k0 = *(const bf16x8*)(krow1);
      bf16x8 a1k1 = *(const bf16x8*)(krow1 + 32);
      // V^T fragments under the pair-permutation: {tile-a 4 keys, tile-b 4 keys}
      bf16x8 av[4];
#pragma unroll
      for (int dt = 0; dt < 4; dt++) {
        const unsigned short* vrow = &VtL[buf][(dt * 16 + lr) * PADV];
        u32x2 lo = *(const u32x2*)(vrow + kta * 16 + lg * 4);
        u32x2 hi = *(const u32x2*)(vrow + ktb * 16 + lg * 4);
        union { u32x4 u; bf16x8 v; } cv;
        cv.u = (u32x4){lo[0], lo[1], hi[0], hi[1]};
        av[dt] = cv.v;
      }
      float mska[4], mskb[4];
      if (masked) {
#pragma unroll
        for (int r = 0; r < 4; r++) {
          mska[r] = (sbs[buf][kta * 16 + lg * 4 + r] == blk) ? 0.f : 32.f;
          mskb[r] = (sbs[buf][ktb * 16 + lg * 4 + r] == blk) ? 0.f : 32.f;
        }
      }
      bf16x8 bq[2];
#pragma unroll
      for (int qt = 0; qt < 2; qt++) {
        f32x4 ca = (f32x4){0.f, 0.f, 0.f, 0.f};
        ca = __builtin_amdgcn_mfma_f32_16x16x32_bf16(a0k0, qf[qt][0], ca, 0, 0, 0);
        ca = __builtin_amdgcn_mfma_f32_16x16x32_bf16(a0k1, qf[qt][1], ca, 0, 0, 0);
        f32x4 cb = (f32x4){0.f, 0.f, 0.f, 0.f};
        cb = __builtin_amdgcn_mfma_f32_16x16x32_bf16(a1k0, qf[qt][0], cb, 0, 0, 0);
        cb = __builtin_amdgcn_mfma_f32_16x16x32_bf16(a1k1, qf[qt][1], cb, 0, 0, 0);
        float wa0 = fexp2(ca[0]), wa1 = fexp2(ca[1]), wa2 = fexp2(ca[2]), wa3 = fexp2(ca[3]);
        float wb0 = fexp2(cb[0]), wb1 = fexp2(cb[1]), wb2 = fexp2(cb[2]), wb3 = fexp2(cb[3]);
        if (masked) {
          wa0 *= mska[0]; wa1 *= mska[1]; wa2 *= mska[2]; wa3 *= mska[3];
          wb0 *= mskb[0]; wb1 *= mskb[1]; wb2 *= mskb[2]; wb3 *= mskb[3];
        }
        union { u32x4 u; bf16x8 v; } cv;
        cv.u = (u32x4){pack2bf(wa0, wa1), pack2bf(wa2, wa3),
                       pack2bf(wb0, wb1), pack2bf(wb2, wb3)};
        bq[qt] = cv.v;
      }
#pragma unroll
      for (int qt = 0; qt < 2; qt++) {
#pragma unroll
        for (int dt = 0; dt < 4; dt++)
          oX[qt][dt] = __builtin_amdgcn_mfma_f32_16x16x32_bf16(av[dt], bq[qt], oX[qt][dt], 0, 0, 0);
        oLS[qt] = __builtin_amdgcn_mfma_f32_16x16x32_bf16(avONE8, bq[qt], oLS[qt], 0, 0, 0);
      }
    }
    __builtin_amdgcn_s_setprio(0);
  };

  // ---- chunks: block0(b0), block1(b1), sample0(b0), sample1(b1) ----
  phase(0, false);
  stage_block(1, 1);       // into other buffer; no pre-barrier needed
  __syncthreads();

  phase(1, false);
  stage_sample(0, 0);
  __syncthreads();

  phase(0, true);
  stage_sample(1, 1);
  __syncthreads();

  phase(1, true);

  // ---- normalize + scatter: out = oX / ls ----
#pragma unroll
  for (int qt = 0; qt < 2; qt++) {
    float l = __shfl(oLS[qt][0], lr);   // lane (lg=0, lr) holds sum for q=lr
    float winv = 1.f / l;
    int qr = qrows[w * 32 + qt * 16 + lr];
    float* op = out + ((size_t)bh * N_ + qr) * D_ + lg * 4;
#pragma unroll
    for (int dt = 0; dt < 4; dt++) {
      float4 o;
      o.x = winv * oX[qt][dt][0];
      o.y = winv * oX[qt][dt][1];
      o.z = winv * oX[qt][dt][2];
      o.w = winv * oX[qt][dt][3];
      *(float4*)(op + dt * 16) = o;
    }
  }
}

extern "C" void kernel_launch(void* const* d_in, const int* in_sizes, int n_in,
                              void* d_out, int out_size, void* d_ws, size_t ws_size,
                              hipStream_t stream) {
  const float* query = (const float*)d_in[0];
  const float* key   = (const float*)d_in[1];
  const float* value = (const float*)d_in[2];
  const float* pd    = (const float*)d_in[3];
  const int*   samp  = (const int*)d_in[4];
  float* out = (float*)d_out;

  char* w = (char*)d_ws;
  size_t o = 0;
  auto alloc = [&](size_t bytes) { void* p = w + o; o = (o + bytes + 255) & ~(size_t)255; return p; };
  int* qh   = (int*)alloc((size_t)BH_ * N_ * 4);
  int* kh   = (int*)alloc((size_t)BH_ * N_ * 4);
  int* qidx = (int*)alloc((size_t)BH_ * N_ * 4);
  int* kidx = (int*)alloc((size_t)BH_ * N_ * 4);

  hash_kernel<<<(2 * BH_ * N_) / 256, 256, 0, stream>>>(query, key, pd, qh, kh);
  sort_kernel<<<2 * BH_, 256, 0, stream>>>(qh, kh, qidx, kidx);
  attn_kernel<<<BH_ * NBLK_, 512, 0, stream>>>(query, key, value, qidx, kidx,
                                               samp, out);
}